// Round 2
// baseline (1103.981 us; speedup 1.0000x reference)
//
#include <hip/hip_runtime.h>
#include <hip/hip_bf16.h>
#include <stdint.h>

#define N_TOK 8192
#define CDIM  1024
#define HDIM  4096
#define NEXP  8
#define BM    256
#define BKK   64

typedef __attribute__((ext_vector_type(8))) short bf16x8;
typedef __attribute__((ext_vector_type(4))) float f32x4;

static __device__ __forceinline__ uint16_t f2bf(float f) {
  union { float f; uint32_t u; } v; v.f = f;
  uint32_t r = v.u + 0x7FFF + ((v.u >> 16) & 1);
  return (uint16_t)(r >> 16);
}

__device__ __forceinline__ void gload_lds16(const void* g, void* l) {
  __builtin_amdgcn_global_load_lds(
      (const __attribute__((address_space(1))) uint32_t*)g,
      (__attribute__((address_space(3))) uint32_t*)l, 16, 0, 0);
}

// ---------------- x -> bf16 ----------------
__global__ void cvt_x_kernel(const float* __restrict__ x, uint16_t* __restrict__ xb) {
  int i = blockIdx.x * 256 + threadIdx.x;   // one thread = 8 elements
  const float4* p = (const float4*)x + (size_t)i * 2;
  float4 a = p[0], b = p[1];
  bf16x8 o;
  o[0] = (short)f2bf(a.x); o[1] = (short)f2bf(a.y);
  o[2] = (short)f2bf(a.z); o[3] = (short)f2bf(a.w);
  o[4] = (short)f2bf(b.x); o[5] = (short)f2bf(b.y);
  o[6] = (short)f2bf(b.z); o[7] = (short)f2bf(b.w);
  *(bf16x8*)(xb + (size_t)i * 8) = o;
}

// ------- transpose+convert: src [R][S] f32 -> dst [S][R] bf16, per expert z; 64x64 tile, float4 loads -------
__global__ void transcvt_kernel(const float* __restrict__ src, uint16_t* __restrict__ dst,
                                int R, int S) {
  __shared__ float tile[64][65];
  size_t base = (size_t)blockIdx.z * R * S;
  int c0 = blockIdx.x * 64, r0 = blockIdx.y * 64;
  int t = threadIdx.x;
#pragma unroll
  for (int q = 0; q < 4; q++) {
    int idx = q * 256 + t;
    int row = idx >> 4, c4 = (idx & 15) * 4;
    float4 v = *(const float4*)&src[base + (size_t)(r0 + row) * S + c0 + c4];
    tile[row][c4] = v.x; tile[row][c4 + 1] = v.y;
    tile[row][c4 + 2] = v.z; tile[row][c4 + 3] = v.w;
  }
  __syncthreads();
#pragma unroll
  for (int q = 0; q < 4; q++) {
    int idx = q * 256 + t;
    int crow = idx >> 4, r4 = (idx & 15) * 4;
    ushort4 o;
    o.x = f2bf(tile[r4 + 0][crow]); o.y = f2bf(tile[r4 + 1][crow]);
    o.z = f2bf(tile[r4 + 2][crow]); o.w = f2bf(tile[r4 + 3][crow]);
    *(ushort4*)&dst[base + (size_t)(c0 + crow) * R + r0 + r4] = o;
  }
}

// ---------------- router: one wave per token ----------------
__global__ void router_kernel(const float* __restrict__ x, const float* __restrict__ Wr,
                              int* __restrict__ cnt, int* __restrict__ te,
                              float* __restrict__ tw) {
  int wid = (blockIdx.x * blockDim.x + threadIdx.x) >> 6;
  int lane = threadIdx.x & 63;
  if (wid >= N_TOK) return;
  const float* xr = x + (size_t)wid * CDIM;
  float p[NEXP];
#pragma unroll
  for (int e = 0; e < NEXP; e++) p[e] = 0.f;
  for (int kk = 0; kk < CDIM / 64; kk++) {
    float xv = xr[kk * 64 + lane];
#pragma unroll
    for (int e = 0; e < NEXP; e++)
      p[e] += xv * Wr[e * CDIM + kk * 64 + lane];
  }
#pragma unroll
  for (int e = 0; e < NEXP; e++) {
    float v = p[e];
#pragma unroll
    for (int s = 32; s > 0; s >>= 1) v += __shfl_xor(v, s);
    p[e] = v;
  }
  if (lane == 0) {
    float m0 = -1e30f, m1 = -1e30f; int i0 = 0, i1 = 0;
#pragma unroll
    for (int e = 0; e < NEXP; e++) {
      float v = p[e];
      if (v > m0) { m1 = m0; i1 = i0; m0 = v; i0 = e; }
      else if (v > m1) { m1 = v; i1 = e; }
    }
    float w0 = 1.f / (1.f + __expf(m1 - m0));
    te[wid] = i0 | (i1 << 16);
    tw[wid] = w0;
    atomicAdd(&cnt[i0], 1);
    atomicAdd(&cnt[i1], 1);
  }
}

__global__ void prefix_kernel(const int* __restrict__ cnt, int* __restrict__ offs,
                              int* __restrict__ fill) {
  if (threadIdx.x == 0) {
    int acc = 0;
    for (int e = 0; e < NEXP; e++) { offs[e] = acc; fill[e] = acc; acc += cnt[e]; }
    offs[NEXP] = acc;
  }
}

__global__ void bucket_kernel(const int* __restrict__ te, const float* __restrict__ tw,
                              int* __restrict__ fill, int* __restrict__ perm,
                              float* __restrict__ pw) {
  int t = blockIdx.x * 256 + threadIdx.x;
  if (t >= N_TOK) return;
  int e01 = te[t];
  int e0 = e01 & 0xffff, e1 = e01 >> 16;
  float w0 = tw[t];
  int p0 = atomicAdd(&fill[e0], 1);
  perm[p0] = t; pw[p0] = w0;
  int p1 = atomicAdd(&fill[e1], 1);
  perm[p1] = t; pw[p1] = 1.f - w0;
}

// ---------------- grouped GEMM, 256x256 tile, BK=64, 8 waves, double-buffered prefetch ----------------
// 1D grid, chunked-XCD swizzle; decode (e, nb, rb) with rb fastest so each XCD owns
// consecutive row-blocks of one (e, nb) panel -> B fetched once per XCD, A L2-resident per expert.
template<bool GATHER, bool RELU2, int NDIM, int KDIM>
__global__ __launch_bounds__(512, 2)
void moe_gemm(const uint16_t* __restrict__ A, const uint16_t* __restrict__ Bt,
              const int* __restrict__ offs, const int* __restrict__ perm,
              const float* __restrict__ pw, uint16_t* __restrict__ hb,
              float* __restrict__ out) {
  const int NB = NDIM / BM;          // n-blocks per expert
  int nwg = gridDim.x;               // = 32 * NB * NEXP, divisible by 8
  int bid = blockIdx.x;
  int wid = (bid & 7) * (nwg >> 3) + (bid >> 3);  // chunked XCD swizzle (bijective)
  int rb_i = wid & 31;
  int rest = wid >> 5;
  int nb = rest % NB;
  int e  = rest / NB;
  int o0 = offs[e];
  int Me = offs[e + 1] - o0;
  int rb = rb_i * BM;
  if (rb >= Me) return;
  int nb0 = nb * BM;

  __shared__ uint16_t smA[2][BM * BKK];   // 2 x 32KB
  __shared__ uint16_t smB[2][BM * BKK];   // 2 x 32KB  (128KB total)

  int tid = threadIdx.x;
  int w = tid >> 6, l = tid & 63;
  int wr = w >> 2, wc = w & 3;           // 2M x 4N waves, wave tile 128x64

  // staging source pointers: chunk c = j*512 + tid -> (row = c>>3, k8 = (c&7)*8)
  const uint16_t* aptr[4];
#pragma unroll
  for (int j = 0; j < 4; j++) {
    int c = j * 512 + tid;
    int gi = o0 + rb + (c >> 3);
    if (gi > 2 * N_TOK - 1) gi = 2 * N_TOK - 1;
    int arow = GATHER ? perm[gi] : gi;
    aptr[j] = A + (size_t)arow * KDIM + (c & 7) * 8;
  }
  const uint16_t* bbase = Bt + (size_t)e * NDIM * KDIM;
  const uint16_t* bptr[4];
#pragma unroll
  for (int j = 0; j < 4; j++) {
    int c = j * 512 + tid;
    bptr[j] = bbase + (size_t)(nb0 + (c >> 3)) * KDIM + (c & 7) * 8;
  }

  f32x4 acc[8][4];
#pragma unroll
  for (int m = 0; m < 8; m++)
#pragma unroll
    for (int n = 0; n < 4; n++)
      acc[m][n] = (f32x4)0.f;

#define STAGE(buf, k0)                                                      \
  do {                                                                      \
    _Pragma("unroll")                                                       \
    for (int j = 0; j < 4; j++) {                                           \
      gload_lds16(aptr[j] + (k0), (char*)&smA[buf][0] + j * 8192 + w * 1024);\
      gload_lds16(bptr[j] + (k0), (char*)&smB[buf][0] + j * 8192 + w * 1024);\
    }                                                                       \
  } while (0)

  const int NT = KDIM / BKK;
  STAGE(0, 0);
  __syncthreads();
  int cur = 0;
  for (int t = 0; t < NT; ++t) {
    if (t + 1 < NT) STAGE(cur ^ 1, (t + 1) * BKK);   // prefetch flies under MFMA
    const uint16_t* sA = &smA[cur][0];
    const uint16_t* sB = &smB[cur][0];
    bf16x8 bfr[4][2];
#pragma unroll
    for (int n = 0; n < 4; n++)
#pragma unroll
      for (int kk = 0; kk < 2; kk++)
        bfr[n][kk] = *(const bf16x8*)&sB[(wc * 64 + n * 16 + (l & 15)) * BKK + kk * 32 + (l >> 4) * 8];
#pragma unroll
    for (int m = 0; m < 8; m++) {
      bf16x8 a0 = *(const bf16x8*)&sA[(wr * 128 + m * 16 + (l & 15)) * BKK + (l >> 4) * 8];
      bf16x8 a1 = *(const bf16x8*)&sA[(wr * 128 + m * 16 + (l & 15)) * BKK + 32 + (l >> 4) * 8];
#pragma unroll
      for (int n = 0; n < 4; n++) {
        acc[m][n] = __builtin_amdgcn_mfma_f32_16x16x32_bf16(a0, bfr[n][0], acc[m][n], 0, 0, 0);
        acc[m][n] = __builtin_amdgcn_mfma_f32_16x16x32_bf16(a1, bfr[n][1], acc[m][n], 0, 0, 0);
      }
    }
    __syncthreads();   // drains vmcnt(0): buf[cur^1] staged; all reads of buf[cur] done
    cur ^= 1;
  }
#undef STAGE

  int cl = l & 15;
  int rg = (l >> 4) * 4;
  if (RELU2) {
#pragma unroll
    for (int m = 0; m < 8; m++) {
#pragma unroll
      for (int jj = 0; jj < 4; jj++) {
        int er = rb + wr * 128 + m * 16 + rg + jj;
        if (er < Me) {
          size_t rowoff = (size_t)(o0 + er) * NDIM;
#pragma unroll
          for (int n = 0; n < 4; n++) {
            int gc = nb0 + wc * 64 + n * 16 + cl;
            float v = acc[m][n][jj];
            v = v > 0.f ? v * v : 0.f;
            hb[rowoff + gc] = f2bf(v);
          }
        }
      }
    }
  } else {
#pragma unroll
    for (int m = 0; m < 8; m++) {
#pragma unroll
      for (int jj = 0; jj < 4; jj++) {
        int er = rb + wr * 128 + m * 16 + rg + jj;
        if (er < Me) {
          int gi = o0 + er;
          int tok = perm[gi];
          float wgt = pw[gi];
          size_t rowoff = (size_t)tok * NDIM;
#pragma unroll
          for (int n = 0; n < 4; n++) {
            int gc = nb0 + wc * 64 + n * 16 + cl;
            atomicAdd(&out[rowoff + gc], wgt * acc[m][n][jj]);
          }
        }
      }
    }
  }
}

extern "C" void kernel_launch(void* const* d_in, const int* in_sizes, int n_in,
                              void* d_out, int out_size, void* d_ws, size_t ws_size,
                              hipStream_t stream) {
  const float* x  = (const float*)d_in[0];
  const float* Wr = (const float*)d_in[1];
  const float* W1 = (const float*)d_in[2];
  const float* W2 = (const float*)d_in[3];
  float* out = (float*)d_out;

  char* ws = (char*)d_ws;
  size_t off = 0;
  uint16_t* xb  = (uint16_t*)(ws + off); off += (size_t)N_TOK * CDIM * 2;
  uint16_t* W1t = (uint16_t*)(ws + off); off += (size_t)NEXP * CDIM * HDIM * 2;
  uint16_t* W2t = (uint16_t*)(ws + off); off += (size_t)NEXP * CDIM * HDIM * 2;
  uint16_t* hb  = (uint16_t*)(ws + off); off += (size_t)2 * N_TOK * HDIM * 2;
  int*   perm = (int*)(ws + off); off += (size_t)2 * N_TOK * 4;
  float* pwt  = (float*)(ws + off); off += (size_t)2 * N_TOK * 4;
  int*   te   = (int*)(ws + off); off += (size_t)N_TOK * 4;
  float* tw   = (float*)(ws + off); off += (size_t)N_TOK * 4;
  int*   cnt  = (int*)(ws + off); off += 16 * 4;
  int*   offs = (int*)(ws + off); off += 16 * 4;
  int*   fill = (int*)(ws + off); off += 16 * 4;

  hipMemsetAsync(d_out, 0, (size_t)out_size * sizeof(float), stream);
  hipMemsetAsync(cnt, 0, 16 * 4, stream);

  cvt_x_kernel<<<4096, 256, 0, stream>>>(x, xb);
  transcvt_kernel<<<dim3(HDIM / 64, CDIM / 64, NEXP), 256, 0, stream>>>(W1, W1t, CDIM, HDIM);
  transcvt_kernel<<<dim3(CDIM / 64, HDIM / 64, NEXP), 256, 0, stream>>>(W2, W2t, HDIM, CDIM);
  router_kernel<<<N_TOK / 4, 256, 0, stream>>>(x, Wr, cnt, te, tw);
  prefix_kernel<<<1, 64, 0, stream>>>(cnt, offs, fill);
  bucket_kernel<<<N_TOK / 256, 256, 0, stream>>>(te, tw, fill, perm, pwt);

  // GEMM1: h = relu^2(x @ W1)  [rows gathered via perm]  M<=8192/expert, N=4096, K=1024
  moe_gemm<true, true, HDIM, CDIM><<<32 * (HDIM / BM) * NEXP, 512, 0, stream>>>(
      xb, W1t, offs, perm, pwt, hb, out);
  // GEMM2: out += gate * (h @ W2)   N=1024, K=4096
  moe_gemm<false, false, CDIM, HDIM><<<32 * (CDIM / BM) * NEXP, 512, 0, stream>>>(
      hb, W2t, offs, perm, pwt, hb, out);
}

// Round 3
// 941.514 us; speedup vs baseline: 1.1726x; 1.1726x over previous
//
#include <hip/hip_runtime.h>
#include <hip/hip_bf16.h>
#include <stdint.h>

#define N_TOK 8192
#define CDIM  1024
#define HDIM  4096
#define NEXP  8
#define BM    128
#define BN    256
#define BKK   64

typedef __attribute__((ext_vector_type(8))) short bf16x8;
typedef __attribute__((ext_vector_type(4))) float f32x4;

static __device__ __forceinline__ uint16_t f2bf(float f) {
  union { float f; uint32_t u; } v; v.f = f;
  uint32_t r = v.u + 0x7FFF + ((v.u >> 16) & 1);
  return (uint16_t)(r >> 16);
}

__device__ __forceinline__ void gload_lds16(const void* g, void* l) {
  __builtin_amdgcn_global_load_lds(
      (const __attribute__((address_space(1))) uint32_t*)g,
      (__attribute__((address_space(3))) uint32_t*)l, 16, 0, 0);
}

// ---------------- x -> bf16 ----------------
__global__ void cvt_x_kernel(const float* __restrict__ x, uint16_t* __restrict__ xb) {
  int i = blockIdx.x * 256 + threadIdx.x;   // one thread = 8 elements
  const float4* p = (const float4*)x + (size_t)i * 2;
  float4 a = p[0], b = p[1];
  bf16x8 o;
  o[0] = (short)f2bf(a.x); o[1] = (short)f2bf(a.y);
  o[2] = (short)f2bf(a.z); o[3] = (short)f2bf(a.w);
  o[4] = (short)f2bf(b.x); o[5] = (short)f2bf(b.y);
  o[6] = (short)f2bf(b.z); o[7] = (short)f2bf(b.w);
  *(bf16x8*)(xb + (size_t)i * 8) = o;
}

// ------- transpose+convert: src [R][S] f32 -> dst [S][R] bf16, per expert z; 64x64 tile -------
__global__ void transcvt_kernel(const float* __restrict__ src, uint16_t* __restrict__ dst,
                                int R, int S) {
  __shared__ float tile[64][65];
  size_t base = (size_t)blockIdx.z * R * S;
  int c0 = blockIdx.x * 64, r0 = blockIdx.y * 64;
  int t = threadIdx.x;
#pragma unroll
  for (int q = 0; q < 4; q++) {
    int idx = q * 256 + t;
    int row = idx >> 4, c4 = (idx & 15) * 4;
    float4 v = *(const float4*)&src[base + (size_t)(r0 + row) * S + c0 + c4];
    tile[row][c4] = v.x; tile[row][c4 + 1] = v.y;
    tile[row][c4 + 2] = v.z; tile[row][c4 + 3] = v.w;
  }
  __syncthreads();
#pragma unroll
  for (int q = 0; q < 4; q++) {
    int idx = q * 256 + t;
    int crow = idx >> 4, r4 = (idx & 15) * 4;
    ushort4 o;
    o.x = f2bf(tile[r4 + 0][crow]); o.y = f2bf(tile[r4 + 1][crow]);
    o.z = f2bf(tile[r4 + 2][crow]); o.w = f2bf(tile[r4 + 3][crow]);
    *(ushort4*)&dst[base + (size_t)(c0 + crow) * R + r0 + r4] = o;
  }
}

// ---------------- router: one wave per token (fp32 x for exact-ish top-k) ----------------
__global__ void router_kernel(const float* __restrict__ x, const float* __restrict__ Wr,
                              int* __restrict__ cnt, int* __restrict__ te,
                              float* __restrict__ tw) {
  int wid = (blockIdx.x * blockDim.x + threadIdx.x) >> 6;
  int lane = threadIdx.x & 63;
  if (wid >= N_TOK) return;
  const float* xr = x + (size_t)wid * CDIM;
  float p[NEXP];
#pragma unroll
  for (int e = 0; e < NEXP; e++) p[e] = 0.f;
  for (int kk = 0; kk < CDIM / 64; kk++) {
    float xv = xr[kk * 64 + lane];
#pragma unroll
    for (int e = 0; e < NEXP; e++)
      p[e] += xv * Wr[e * CDIM + kk * 64 + lane];
  }
#pragma unroll
  for (int e = 0; e < NEXP; e++) {
    float v = p[e];
#pragma unroll
    for (int s = 32; s > 0; s >>= 1) v += __shfl_xor(v, s);
    p[e] = v;
  }
  if (lane == 0) {
    float m0 = -1e30f, m1 = -1e30f; int i0 = 0, i1 = 0;
#pragma unroll
    for (int e = 0; e < NEXP; e++) {
      float v = p[e];
      if (v > m0) { m1 = m0; i1 = i0; m0 = v; i0 = e; }
      else if (v > m1) { m1 = v; i1 = e; }
    }
    float w0 = 1.f / (1.f + __expf(m1 - m0));
    te[wid] = i0 | (i1 << 16);
    tw[wid] = w0;
    atomicAdd(&cnt[i0], 1);
    atomicAdd(&cnt[i1], 1);
  }
}

__global__ void prefix_kernel(const int* __restrict__ cnt, int* __restrict__ offs,
                              int* __restrict__ fill) {
  if (threadIdx.x == 0) {
    int acc = 0;
    for (int e = 0; e < NEXP; e++) { offs[e] = acc; fill[e] = acc; acc += cnt[e]; }
    offs[NEXP] = acc;
  }
}

__global__ void bucket_kernel(const int* __restrict__ te, const float* __restrict__ tw,
                              int* __restrict__ fill, int* __restrict__ perm,
                              float* __restrict__ pw) {
  int t = blockIdx.x * 256 + threadIdx.x;
  if (t >= N_TOK) return;
  int e01 = te[t];
  int e0 = e01 & 0xffff, e1 = e01 >> 16;
  float w0 = tw[t];
  int p0 = atomicAdd(&fill[e0], 1);
  perm[p0] = t; pw[p0] = w0;
  int p1 = atomicAdd(&fill[e1], 1);
  perm[p1] = t; pw[p1] = 1.f - w0;
}

// ---------------- grouped GEMM: 128x256 tile, BK=64, 3 LDS buffers, counted vmcnt ----------------
// T2: k-chunk XOR-swizzle (slot ^= row&7) applied on the GLOBAL source (linear LDS dest,
// rule #21) and on ds_read addresses -> conflict-free b128 reads.
// T3/T4: distance-2 prefetch, one s_barrier per K-tile, vmcnt(6) steady state (never 0).
// T5: setprio around the 32-MFMA cluster.
template<bool GATHER, bool RELU2, int NDIM, int KDIM>
__global__ __launch_bounds__(512, 2)
void moe_gemm(const uint16_t* __restrict__ A, const uint16_t* __restrict__ Bt,
              const int* __restrict__ offs, const int* __restrict__ perm,
              const float* __restrict__ pw, uint16_t* __restrict__ hb,
              float* __restrict__ out) {
  const int NB = NDIM / BN;
  const int RBMAX = N_TOK / BM;        // 64
  int nwg = gridDim.x;                 // 64 * NB * NEXP, divisible by 8
  int bid = blockIdx.x;
  int wid = (bid & 7) * (nwg >> 3) + (bid >> 3);  // chunked XCD swizzle (bijective)
  int rb_i = wid % RBMAX;              // rb fastest: XCD chunk = one expert's panel set
  int rest = wid / RBMAX;
  int nb = rest % NB;
  int e  = rest / NB;
  int o0 = offs[e];
  int Me = offs[e + 1] - o0;
  int rb = rb_i * BM;
  if (rb >= Me) return;
  int nb0 = nb * BN;

  __shared__ uint16_t smA[3][BM * BKK];   // 3 x 16KB
  __shared__ uint16_t smB[3][BN * BKK];   // 3 x 32KB   (144KB total)

  int tid = threadIdx.x;
  int w = tid >> 6, l = tid & 63;
  int wr = w >> 2, wc = w & 3;           // 2M x 4N waves, wave tile 64x64

  // staging source pointers, swizzle folded in: dest chunk c=(j*512+tid) -> (row=c>>3, slot=c&7)
  // holds global k-chunk (slot ^ (row&7))
  const uint16_t* aptr[2];
#pragma unroll
  for (int j = 0; j < 2; j++) {
    int c = j * 512 + tid;
    int row = c >> 3, slot = c & 7;
    int gi = o0 + rb + row;
    if (gi > 2 * N_TOK - 1) gi = 2 * N_TOK - 1;
    int arow = GATHER ? perm[gi] : gi;
    aptr[j] = A + (size_t)arow * KDIM + ((slot ^ (row & 7)) << 3);
  }
  const uint16_t* bbase = Bt + (size_t)e * NDIM * KDIM;
  const uint16_t* bptr[4];
#pragma unroll
  for (int j = 0; j < 4; j++) {
    int c = j * 512 + tid;
    int row = c >> 3, slot = c & 7;
    bptr[j] = bbase + (size_t)(nb0 + row) * KDIM + ((slot ^ (row & 7)) << 3);
  }

  f32x4 acc[4][4];
#pragma unroll
  for (int m = 0; m < 4; m++)
#pragma unroll
    for (int n = 0; n < 4; n++)
      acc[m][n] = (f32x4)0.f;

#define STAGE(bi, kt)                                                         \
  do {                                                                        \
    _Pragma("unroll")                                                         \
    for (int j = 0; j < 2; j++)                                               \
      gload_lds16(aptr[j] + (kt) * BKK, (char*)&smA[bi][0] + j * 8192 + w * 1024); \
    _Pragma("unroll")                                                         \
    for (int j = 0; j < 4; j++)                                               \
      gload_lds16(bptr[j] + (kt) * BKK, (char*)&smB[bi][0] + j * 8192 + w * 1024); \
  } while (0)

  const int NT = KDIM / BKK;
  STAGE(0, 0);
  STAGE(1, 1);                          // 12 loads in flight
  int cb = 0, sb = 2;
  for (int t = 0; t < NT; ++t) {
    // buf[cb] (staged 2 phases ago) ready once <=6 newer loads remain
    if (t < NT - 1) asm volatile("s_waitcnt vmcnt(6)" ::: "memory");
    else            asm volatile("s_waitcnt vmcnt(0)" ::: "memory");
    __builtin_amdgcn_sched_barrier(0);
    asm volatile("s_barrier" ::: "memory");   // all waves past their vmcnt; prev reads done
    if (t + 2 < NT) STAGE(sb, t + 2);         // overwrite buffer freed at phase t-1
    const uint16_t* sA = &smA[cb][0];
    const uint16_t* sB = &smB[cb][0];
    bf16x8 af[4][2], bfv[4][2];
#pragma unroll
    for (int m = 0; m < 4; m++)
#pragma unroll
      for (int kk = 0; kk < 2; kk++) {
        int row = wr * 64 + m * 16 + (l & 15);
        int s = kk * 4 + (l >> 4);
        af[m][kk] = *(const bf16x8*)&sA[row * BKK + ((s ^ (row & 7)) << 3)];
      }
#pragma unroll
    for (int n = 0; n < 4; n++)
#pragma unroll
      for (int kk = 0; kk < 2; kk++) {
        int row = wc * 64 + n * 16 + (l & 15);
        int s = kk * 4 + (l >> 4);
        bfv[n][kk] = *(const bf16x8*)&sB[row * BKK + ((s ^ (row & 7)) << 3)];
      }
    __builtin_amdgcn_s_setprio(1);
#pragma unroll
    for (int m = 0; m < 4; m++)
#pragma unroll
      for (int n = 0; n < 4; n++) {
        acc[m][n] = __builtin_amdgcn_mfma_f32_16x16x32_bf16(af[m][0], bfv[n][0], acc[m][n], 0, 0, 0);
        acc[m][n] = __builtin_amdgcn_mfma_f32_16x16x32_bf16(af[m][1], bfv[n][1], acc[m][n], 0, 0, 0);
      }
    __builtin_amdgcn_s_setprio(0);
    cb = (cb == 2) ? 0 : cb + 1;
    sb = (sb == 2) ? 0 : sb + 1;
  }
#undef STAGE

  int cl = l & 15;
  int rg = (l >> 4) * 4;
  if (RELU2) {
#pragma unroll
    for (int m = 0; m < 4; m++) {
#pragma unroll
      for (int jj = 0; jj < 4; jj++) {
        int er = rb + wr * 64 + m * 16 + rg + jj;
        if (er < Me) {
          size_t rowoff = (size_t)(o0 + er) * NDIM;
#pragma unroll
          for (int n = 0; n < 4; n++) {
            int gc = nb0 + wc * 64 + n * 16 + cl;
            float v = acc[m][n][jj];
            v = v > 0.f ? v * v : 0.f;
            hb[rowoff + gc] = f2bf(v);
          }
        }
      }
    }
  } else {
#pragma unroll
    for (int m = 0; m < 4; m++) {
#pragma unroll
      for (int jj = 0; jj < 4; jj++) {
        int er = rb + wr * 64 + m * 16 + rg + jj;
        if (er < Me) {
          int gi = o0 + er;
          int tok = perm[gi];
          float wgt = pw[gi];
          size_t rowoff = (size_t)tok * NDIM;
#pragma unroll
          for (int n = 0; n < 4; n++) {
            int gc = nb0 + wc * 64 + n * 16 + cl;
            atomicAdd(&out[rowoff + gc], wgt * acc[m][n][jj]);
          }
        }
      }
    }
  }
}

extern "C" void kernel_launch(void* const* d_in, const int* in_sizes, int n_in,
                              void* d_out, int out_size, void* d_ws, size_t ws_size,
                              hipStream_t stream) {
  const float* x  = (const float*)d_in[0];
  const float* Wr = (const float*)d_in[1];
  const float* W1 = (const float*)d_in[2];
  const float* W2 = (const float*)d_in[3];
  float* out = (float*)d_out;

  char* ws = (char*)d_ws;
  size_t off = 0;
  uint16_t* xb  = (uint16_t*)(ws + off); off += (size_t)N_TOK * CDIM * 2;
  uint16_t* W1t = (uint16_t*)(ws + off); off += (size_t)NEXP * CDIM * HDIM * 2;
  uint16_t* W2t = (uint16_t*)(ws + off); off += (size_t)NEXP * CDIM * HDIM * 2;
  uint16_t* hb  = (uint16_t*)(ws + off); off += (size_t)2 * N_TOK * HDIM * 2;
  int*   perm = (int*)(ws + off); off += (size_t)2 * N_TOK * 4;
  float* pwt  = (float*)(ws + off); off += (size_t)2 * N_TOK * 4;
  int*   te   = (int*)(ws + off); off += (size_t)N_TOK * 4;
  float* tw   = (float*)(ws + off); off += (size_t)N_TOK * 4;
  int*   cnt  = (int*)(ws + off); off += 16 * 4;
  int*   offs = (int*)(ws + off); off += 16 * 4;
  int*   fill = (int*)(ws + off); off += 16 * 4;

  hipMemsetAsync(d_out, 0, (size_t)out_size * sizeof(float), stream);
  hipMemsetAsync(cnt, 0, 16 * 4, stream);

  cvt_x_kernel<<<4096, 256, 0, stream>>>(x, xb);
  transcvt_kernel<<<dim3(HDIM / 64, CDIM / 64, NEXP), 256, 0, stream>>>(W1, W1t, CDIM, HDIM);
  transcvt_kernel<<<dim3(CDIM / 64, HDIM / 64, NEXP), 256, 0, stream>>>(W2, W2t, HDIM, CDIM);
  router_kernel<<<N_TOK / 4, 256, 0, stream>>>(x, Wr, cnt, te, tw);
  prefix_kernel<<<1, 64, 0, stream>>>(cnt, offs, fill);
  bucket_kernel<<<N_TOK / 256, 256, 0, stream>>>(te, tw, fill, perm, pwt);

  // GEMM1: h = relu^2(x @ W1)  [rows gathered via perm]  N=4096, K=1024
  moe_gemm<true, true, HDIM, CDIM><<<(N_TOK / BM) * (HDIM / BN) * NEXP, 512, 0, stream>>>(
      xb, W1t, offs, perm, pwt, hb, out);
  // GEMM2: out += gate * (h @ W2)   N=1024, K=4096
  moe_gemm<false, false, CDIM, HDIM><<<(N_TOK / BM) * (CDIM / BN) * NEXP, 512, 0, stream>>>(
      hb, W2t, offs, perm, pwt, hb, out);
}

// Round 4
// 886.470 us; speedup vs baseline: 1.2454x; 1.0621x over previous
//
#include <hip/hip_runtime.h>
#include <hip/hip_bf16.h>
#include <stdint.h>

#define N_TOK 8192
#define CDIM  1024
#define HDIM  4096
#define NEXP  8
#define BM    256
#define BN    256
#define BKK   64

typedef __attribute__((ext_vector_type(8))) short bf16x8;
typedef __attribute__((ext_vector_type(4))) float f32x4;

static __device__ __forceinline__ uint16_t f2bf(float f) {
  union { float f; uint32_t u; } v; v.f = f;
  uint32_t r = v.u + 0x7FFF + ((v.u >> 16) & 1);
  return (uint16_t)(r >> 16);
}

__device__ __forceinline__ void gload_lds16(const void* g, void* l) {
  __builtin_amdgcn_global_load_lds(
      (const __attribute__((address_space(1))) uint32_t*)g,
      (__attribute__((address_space(3))) uint32_t*)l, 16, 0, 0);
}

// ------- transpose+convert: src [R][S] f32 -> dst [S][R] bf16; 128(r)x64(c) tile -------
__global__ void transcvt_kernel(const float* __restrict__ src, uint16_t* __restrict__ dst,
                                int R, int S) {
  __shared__ float tile[128][65];
  size_t base = (size_t)blockIdx.z * (size_t)R * S;
  int c0 = blockIdx.x * 64, r0 = blockIdx.y * 128;
  int t = threadIdx.x;
#pragma unroll
  for (int q = 0; q < 8; q++) {
    int idx = q * 256 + t;
    int row = idx >> 4, c4 = (idx & 15) * 4;
    float4 v = *(const float4*)&src[base + (size_t)(r0 + row) * S + c0 + c4];
    tile[row][c4] = v.x; tile[row][c4 + 1] = v.y;
    tile[row][c4 + 2] = v.z; tile[row][c4 + 3] = v.w;
  }
  __syncthreads();
#pragma unroll
  for (int q = 0; q < 4; q++) {
    int idx = q * 256 + t;
    int crow = idx >> 4, r8 = (idx & 15) * 8;
    bf16x8 o;
#pragma unroll
    for (int k = 0; k < 8; k++) o[k] = (short)f2bf(tile[r8 + k][crow]);
    *(bf16x8*)&dst[base + (size_t)(c0 + crow) * R + r0 + r8] = o;
  }
}

// ---------------- router (+ fused x->bf16): one wave per token ----------------
__global__ void router_kernel(const float* __restrict__ x, const float* __restrict__ Wr,
                              int* __restrict__ cnt, int* __restrict__ te,
                              float* __restrict__ tw, uint16_t* __restrict__ xb) {
  int wid = (blockIdx.x * blockDim.x + threadIdx.x) >> 6;
  int lane = threadIdx.x & 63;
  if (wid >= N_TOK) return;
  const float* xr = x + (size_t)wid * CDIM;
  uint16_t* xbr = xb + (size_t)wid * CDIM;
  float p[NEXP];
#pragma unroll
  for (int e = 0; e < NEXP; e++) p[e] = 0.f;
  for (int kk = 0; kk < CDIM / 64; kk++) {
    float xv = xr[kk * 64 + lane];
    xbr[kk * 64 + lane] = f2bf(xv);
#pragma unroll
    for (int e = 0; e < NEXP; e++)
      p[e] += xv * Wr[e * CDIM + kk * 64 + lane];
  }
#pragma unroll
  for (int e = 0; e < NEXP; e++) {
    float v = p[e];
#pragma unroll
    for (int s = 32; s > 0; s >>= 1) v += __shfl_xor(v, s);
    p[e] = v;
  }
  if (lane == 0) {
    float m0 = -1e30f, m1 = -1e30f; int i0 = 0, i1 = 0;
#pragma unroll
    for (int e = 0; e < NEXP; e++) {
      float v = p[e];
      if (v > m0) { m1 = m0; i1 = i0; m0 = v; i0 = e; }
      else if (v > m1) { m1 = v; i1 = e; }
    }
    float w0 = 1.f / (1.f + __expf(m1 - m0));
    te[wid] = i0 | (i1 << 16);
    tw[wid] = w0;
    atomicAdd(&cnt[i0], 1);
    atomicAdd(&cnt[i1], 1);
  }
}

__global__ void prefix_kernel(const int* __restrict__ cnt, int* __restrict__ offs,
                              int* __restrict__ fill) {
  if (threadIdx.x == 0) {
    int acc = 0;
    for (int e = 0; e < NEXP; e++) { offs[e] = acc; fill[e] = acc; acc += cnt[e]; }
    offs[NEXP] = acc;
  }
}

__global__ void bucket_kernel(const int* __restrict__ te, const float* __restrict__ tw,
                              int* __restrict__ fill, int* __restrict__ perm,
                              float* __restrict__ pw) {
  int t = blockIdx.x * 256 + threadIdx.x;
  if (t >= N_TOK) return;
  int e01 = te[t];
  int e0 = e01 & 0xffff, e1 = e01 >> 16;
  float w0 = tw[t];
  int p0 = atomicAdd(&fill[e0], 1);
  perm[p0] = t; pw[p0] = w0;
  int p1 = atomicAdd(&fill[e1], 1);
  perm[p1] = t; pw[p1] = 1.f - w0;
}

// ---- grouped GEMM: 256x256 tile, BK=64, 8 waves (2Mx4N, wave tile 128x64), 2 LDS bufs,
// ---- 4 phases/K-tile (m201-style), XOR-swizzled staging (zero bank conflicts, r3-verified).
template<bool GATHER, bool RELU2, int NDIM, int KDIM>
__global__ __launch_bounds__(512, 2)
void moe_gemm(const uint16_t* __restrict__ A, const uint16_t* __restrict__ Bt,
              const int* __restrict__ offs, const int* __restrict__ perm,
              const float* __restrict__ pw, uint16_t* __restrict__ hb,
              float* __restrict__ out) {
  const int NB = NDIM / BN;
  const int RBMAX = 2 * N_TOK / BM;    // 64
  int nwg = gridDim.x;                 // RBMAX * NB * NEXP, divisible by 8
  int bid = blockIdx.x;
  int wid = (bid & 7) * (nwg >> 3) + (bid >> 3);  // chunked XCD swizzle (bijective)
  int rb_i = wid % RBMAX;
  int rest = wid / RBMAX;
  int nb = rest % NB;
  int e  = rest / NB;
  int o0 = offs[e];
  int Me = offs[e + 1] - o0;
  int rb = rb_i * BM;
  if (rb >= Me) return;
  int nb0 = nb * BN;

  __shared__ uint16_t smA[2][BM * BKK];   // 2 x 32KB
  __shared__ uint16_t smB[2][BN * BKK];   // 2 x 32KB  (128KB)

  int tid = threadIdx.x;
  int w = tid >> 6, l = tid & 63;
  int wr = w >> 2, wc = w & 3;            // wave tile: rows [wr*128,+128), cols [wc*64,+64)
  int cl = l & 15;
  int kh = l >> 4;                        // 0..3

  // staging source pointers (XOR swizzle folded into global k-offset)
  const uint16_t* aptr[4];
#pragma unroll
  for (int j = 0; j < 4; j++) {
    int c = j * 512 + tid;
    int row = c >> 3, slot = c & 7;
    int gi = o0 + rb + row;
    if (gi > 2 * N_TOK - 1) gi = 2 * N_TOK - 1;
    int arow = GATHER ? perm[gi] : gi;
    aptr[j] = A + (size_t)arow * KDIM + ((slot ^ (row & 7)) << 3);
  }
  const uint16_t* bbase = Bt + (size_t)e * NDIM * KDIM;
  const uint16_t* bptr[4];
#pragma unroll
  for (int j = 0; j < 4; j++) {
    int c = j * 512 + tid;
    int row = c >> 3, slot = c & 7;
    bptr[j] = bbase + (size_t)(nb0 + row) * KDIM + ((slot ^ (row & 7)) << 3);
  }

  f32x4 acc[8][4];
#pragma unroll
  for (int m = 0; m < 8; m++)
#pragma unroll
    for (int n = 0; n < 4; n++)
      acc[m][n] = (f32x4)0.f;

#define STAGE_A(bi, kt)                                                        \
  do { _Pragma("unroll")                                                       \
    for (int j = 0; j < 4; j++)                                                \
      gload_lds16(aptr[j] + (kt) * BKK, (char*)&smA[bi][0] + j * 8192 + tid * 16); \
  } while (0)
#define STAGE_B(bi, kt)                                                        \
  do { _Pragma("unroll")                                                       \
    for (int j = 0; j < 4; j++)                                                \
      gload_lds16(bptr[j] + (kt) * BKK, (char*)&smB[bi][0] + j * 8192 + tid * 16); \
  } while (0)

  // swizzled LDS fragment read: row-major [rows][BKK], 16B slot s XOR'd by row&7
#define LDSF(base, row, s) (*(const bf16x8*)&(base)[(row) * BKK + ((((s)) ^ ((row) & 7)) << 3)])

#define PH_SYNC()                                              \
  asm volatile("s_barrier" ::: "memory");                      \
  asm volatile("s_waitcnt lgkmcnt(0)" ::: "memory");           \
  __builtin_amdgcn_sched_barrier(0)

  const int NT = KDIM / BKK;
  STAGE_A(0, 0);
  STAGE_B(0, 0);
  asm volatile("s_waitcnt vmcnt(0)" ::: "memory");
  __builtin_amdgcn_sched_barrier(0);
  asm volatile("s_barrier" ::: "memory");

  bf16x8 aF[4][2], b01[2][2], b23[2][2];
  for (int t = 0; t < NT; ++t) {
    int cur = t & 1, nxt = cur ^ 1;
    const uint16_t* sA = &smA[cur][0];
    const uint16_t* sB = &smB[cur][0];
    // ---- phase 0: read A m0-3 + B n0-1 ; stage next A ; MFMA (m0-3 x n0-1)
#pragma unroll
    for (int m = 0; m < 4; m++)
#pragma unroll
      for (int kk = 0; kk < 2; kk++)
        aF[m][kk] = LDSF(sA, wr * 128 + m * 16 + cl, kk * 4 + kh);
#pragma unroll
    for (int n = 0; n < 2; n++)
#pragma unroll
      for (int kk = 0; kk < 2; kk++)
        b01[n][kk] = LDSF(sB, wc * 64 + n * 16 + cl, kk * 4 + kh);
    if (t + 1 < NT) STAGE_A(nxt, t + 1);
    PH_SYNC();
    __builtin_amdgcn_s_setprio(1);
#pragma unroll
    for (int m = 0; m < 4; m++)
#pragma unroll
      for (int n = 0; n < 2; n++) {
        acc[m][n] = __builtin_amdgcn_mfma_f32_16x16x32_bf16(aF[m][0], b01[n][0], acc[m][n], 0, 0, 0);
        acc[m][n] = __builtin_amdgcn_mfma_f32_16x16x32_bf16(aF[m][1], b01[n][1], acc[m][n], 0, 0, 0);
      }
    __builtin_amdgcn_s_setprio(0);
    asm volatile("s_barrier" ::: "memory");
    // ---- phase 1: read B n2-3 ; stage next B ; MFMA (m0-3 x n2-3)
#pragma unroll
    for (int n = 0; n < 2; n++)
#pragma unroll
      for (int kk = 0; kk < 2; kk++)
        b23[n][kk] = LDSF(sB, wc * 64 + (n + 2) * 16 + cl, kk * 4 + kh);
    if (t + 1 < NT) STAGE_B(nxt, t + 1);
    PH_SYNC();
    __builtin_amdgcn_s_setprio(1);
#pragma unroll
    for (int m = 0; m < 4; m++)
#pragma unroll
      for (int n = 0; n < 2; n++) {
        acc[m][n + 2] = __builtin_amdgcn_mfma_f32_16x16x32_bf16(aF[m][0], b23[n][0], acc[m][n + 2], 0, 0, 0);
        acc[m][n + 2] = __builtin_amdgcn_mfma_f32_16x16x32_bf16(aF[m][1], b23[n][1], acc[m][n + 2], 0, 0, 0);
      }
    __builtin_amdgcn_s_setprio(0);
    asm volatile("s_barrier" ::: "memory");
    // ---- phase 2: read A m4-7 ; MFMA (m4-7 x n2-3)
#pragma unroll
    for (int m = 0; m < 4; m++)
#pragma unroll
      for (int kk = 0; kk < 2; kk++)
        aF[m][kk] = LDSF(sA, wr * 128 + (m + 4) * 16 + cl, kk * 4 + kh);
    PH_SYNC();
    __builtin_amdgcn_s_setprio(1);
#pragma unroll
    for (int m = 0; m < 4; m++)
#pragma unroll
      for (int n = 0; n < 2; n++) {
        acc[m + 4][n + 2] = __builtin_amdgcn_mfma_f32_16x16x32_bf16(aF[m][0], b23[n][0], acc[m + 4][n + 2], 0, 0, 0);
        acc[m + 4][n + 2] = __builtin_amdgcn_mfma_f32_16x16x32_bf16(aF[m][1], b23[n][1], acc[m + 4][n + 2], 0, 0, 0);
      }
    __builtin_amdgcn_s_setprio(0);
    asm volatile("s_barrier" ::: "memory");
    // ---- phase 3: re-read B n0-1 ; counted-drain for next tile ; MFMA (m4-7 x n0-1)
#pragma unroll
    for (int n = 0; n < 2; n++)
#pragma unroll
      for (int kk = 0; kk < 2; kk++)
        b01[n][kk] = LDSF(sB, wc * 64 + n * 16 + cl, kk * 4 + kh);
    if (t + 1 < NT) {  // stages for tile t+1 issued >=2 phases ago -> near-zero stall
      asm volatile("s_waitcnt vmcnt(0)" ::: "memory");
      __builtin_amdgcn_sched_barrier(0);
    }
    PH_SYNC();
    __builtin_amdgcn_s_setprio(1);
#pragma unroll
    for (int m = 0; m < 4; m++)
#pragma unroll
      for (int n = 0; n < 2; n++) {
        acc[m + 4][n] = __builtin_amdgcn_mfma_f32_16x16x32_bf16(aF[m][0], b01[n][0], acc[m + 4][n], 0, 0, 0);
        acc[m + 4][n] = __builtin_amdgcn_mfma_f32_16x16x32_bf16(aF[m][1], b01[n][1], acc[m + 4][n], 0, 0, 0);
      }
    __builtin_amdgcn_s_setprio(0);
    asm volatile("s_barrier" ::: "memory");
  }
#undef STAGE_A
#undef STAGE_B
#undef LDSF
#undef PH_SYNC

  int rg = (l >> 4) * 4;
  if (RELU2) {
#pragma unroll
    for (int m = 0; m < 8; m++) {
#pragma unroll
      for (int jj = 0; jj < 4; jj++) {
        int er = rb + wr * 128 + m * 16 + rg + jj;
        if (er < Me) {
          size_t rowoff = (size_t)(o0 + er) * NDIM;
#pragma unroll
          for (int n = 0; n < 4; n++) {
            int gc = nb0 + wc * 64 + n * 16 + cl;
            float v = acc[m][n][jj];
            v = v > 0.f ? v * v : 0.f;
            hb[rowoff + gc] = f2bf(v);
          }
        }
      }
    }
  } else {
#pragma unroll
    for (int m = 0; m < 8; m++) {
#pragma unroll
      for (int jj = 0; jj < 4; jj++) {
        int er = rb + wr * 128 + m * 16 + rg + jj;
        if (er < Me) {
          int gi = o0 + er;
          int tok = perm[gi];
          float wgt = pw[gi];
          size_t rowoff = (size_t)tok * NDIM;
#pragma unroll
          for (int n = 0; n < 4; n++) {
            int gc = nb0 + wc * 64 + n * 16 + cl;
            atomicAdd(&out[rowoff + gc], wgt * acc[m][n][jj]);
          }
        }
      }
    }
  }
}

extern "C" void kernel_launch(void* const* d_in, const int* in_sizes, int n_in,
                              void* d_out, int out_size, void* d_ws, size_t ws_size,
                              hipStream_t stream) {
  const float* x  = (const float*)d_in[0];
  const float* Wr = (const float*)d_in[1];
  const float* W1 = (const float*)d_in[2];
  const float* W2 = (const float*)d_in[3];
  float* out = (float*)d_out;

  char* ws = (char*)d_ws;
  size_t off = 0;
  uint16_t* xb  = (uint16_t*)(ws + off); off += (size_t)N_TOK * CDIM * 2;
  uint16_t* W1t = (uint16_t*)(ws + off); off += (size_t)NEXP * CDIM * HDIM * 2;
  uint16_t* W2t = (uint16_t*)(ws + off); off += (size_t)NEXP * CDIM * HDIM * 2;
  uint16_t* hb  = (uint16_t*)(ws + off); off += (size_t)2 * N_TOK * HDIM * 2;
  int*   perm = (int*)(ws + off); off += (size_t)2 * N_TOK * 4;
  float* pwt  = (float*)(ws + off); off += (size_t)2 * N_TOK * 4;
  int*   te   = (int*)(ws + off); off += (size_t)N_TOK * 4;
  float* tw   = (float*)(ws + off); off += (size_t)N_TOK * 4;
  int*   cnt  = (int*)(ws + off); off += 16 * 4;
  int*   offs = (int*)(ws + off); off += 16 * 4;
  int*   fill = (int*)(ws + off); off += 16 * 4;

  hipMemsetAsync(d_out, 0, (size_t)out_size * sizeof(float), stream);
  hipMemsetAsync(cnt, 0, 16 * 4, stream);

  router_kernel<<<N_TOK / 4, 256, 0, stream>>>(x, Wr, cnt, te, tw, xb);
  transcvt_kernel<<<dim3(HDIM / 64, CDIM / 128, NEXP), 256, 0, stream>>>(W1, W1t, CDIM, HDIM);
  transcvt_kernel<<<dim3(CDIM / 64, HDIM / 128, NEXP), 256, 0, stream>>>(W2, W2t, HDIM, CDIM);
  prefix_kernel<<<1, 64, 0, stream>>>(cnt, offs, fill);
  bucket_kernel<<<N_TOK / 256, 256, 0, stream>>>(te, tw, fill, perm, pwt);

  // GEMM1: h = relu^2(x @ W1)  [rows gathered via perm]  N=4096, K=1024
  moe_gemm<true, true, HDIM, CDIM>
      <<<(2 * N_TOK / BM) * (HDIM / BN) * NEXP, 512, 0, stream>>>(
      xb, W1t, offs, perm, pwt, hb, out);
  // GEMM2: out += gate * (h @ W2)   N=1024, K=4096
  moe_gemm<false, false, CDIM, HDIM>
      <<<(2 * N_TOK / BM) * (CDIM / BN) * NEXP, 512, 0, stream>>>(
      hb, W2t, offs, perm, pwt, hb, out);
}